// Round 9
// baseline (323.614 us; speedup 1.0000x reference)
//
#include <hip/hip_runtime.h>
#include <math.h>

#define EPSF 1e-20f
static constexpr int N  = 32;
static constexpr int Hh = 192;
static constexpr int Ww = 192;
static constexpr int Bb = 2;
static constexpr int HW = Hh * Ww;            // 36864

// workspace layout (bytes)
static constexpr size_t OFFB_WDFRAG  = 0;          // 9*4*32*8 bf16     = 18432 B
static constexpr size_t OFFB_WPROP   = 36864;      // 32*4 fp32         = 512 B
static constexpr size_t OFFB_WPOW    = 37376;      // 32*8 fp32         = 1024 B
static constexpr size_t OFFB_WFRAG   = 40960;      // 9*16*128*8 bf16   = 294912 B
static constexpr size_t OFFB_CE_BF   = 335872;     // 2*HW*128 bf16     = 18874368 B
static constexpr size_t OFFB_ECE_BF  = OFFB_CE_BF + (size_t)2 * HW * 128 * 2;
static constexpr size_t OFFB_X_BF    = OFFB_ECE_BF + (size_t)2 * HW * 128 * 2;  // 16 planes x HW x 16B = 9.4 MB

static constexpr size_t OUT0_SZ  = (size_t)4 * N * HW;      // 4,718,592
static constexpr size_t EOUT_SZ  = (size_t)Bb * N * 4 * HW; // 9,437,184

typedef short bf16x8 __attribute__((ext_vector_type(8)));
typedef float f32x4  __attribute__((ext_vector_type(4)));

__device__ __forceinline__ float softplusf(float x) { return log1pf(expf(x)); }
__device__ __forceinline__ float sigmf(float x)     { return 1.f / (1.f + expf(-x)); }
__device__ __forceinline__ unsigned short f2bf(float f) {
    unsigned int u = __float_as_uint(f);
    u = (u + 0x7fffu + ((u >> 16) & 1u)) >> 16;   // RNE
    return (unsigned short)u;
}
__device__ __forceinline__ float frcp(float x) { return __builtin_amdgcn_rcpf(x); }
// unaligned-tolerant float4 load (4B-aligned ok)
__device__ __forceinline__ f32x4 load4u(const float* p) {
    f32x4 v; __builtin_memcpy(&v, p, 16); return v;
}
// packed bf16 elementwise multiply (round-half-up repack; inputs in [0,1])
__device__ __forceinline__ bf16x8 bfmul8(bf16x8 a, bf16x8 b) {
    union U { bf16x8 v; unsigned int u[4]; };
    U ua, ub, r; ua.v = a; ub.v = b;
    #pragma unroll
    for (int i = 0; i < 4; ++i) {
        float alo = __uint_as_float(ua.u[i] << 16);
        float ahi = __uint_as_float(ua.u[i] & 0xffff0000u);
        float blo = __uint_as_float(ub.u[i] << 16);
        float bhi = __uint_as_float(ub.u[i] & 0xffff0000u);
        unsigned int lo = __float_as_uint(alo * blo);
        unsigned int hi = __float_as_uint(ahi * bhi);
        lo = (lo + 0x8000u) >> 16;
        hi = (hi + 0x8000u) & 0xffff0000u;
        r.u[i] = hi | lo;
    }
    return r.v;
}

// direct global -> LDS, 16 bytes per lane (LDS dst must be base + lane*16)
typedef __attribute__((address_space(1))) unsigned int ga_u32;
typedef __attribute__((address_space(3))) unsigned int ls_u32;
__device__ __forceinline__ void gload_lds16(const void* g, void* l) {
    __builtin_amdgcn_global_load_lds((ga_u32*)g, (ls_u32*)l, 16, 0, 0);
}

// ---------------------------------------------------------------- weights ---
__global__ void prep_weights(const float* __restrict__ Wcd, const float* __restrict__ Wsd,
                             const float* __restrict__ Wce, const float* __restrict__ Wse0,
                             const float* __restrict__ Wse1, const float* __restrict__ Wse3,
                             const float* __restrict__ Wdir, const float* __restrict__ Wpow,
                             const float* __restrict__ Wprop, char* __restrict__ wsb)
{
    __shared__ float s_wcd[32][32];
    __shared__ float s_wce[32][32];
    __shared__ float s_wsd[32][9];
    __shared__ float s_wse[32][4][9];
    __shared__ float s_wdir[4][32][4];
    const int tid = threadIdx.x;

    if (tid < 64) {
        int o = tid & 31;
        const float* src = (tid < 32) ? Wcd : Wce;
        float s = 0.f;
        for (int i = 0; i < 32; ++i) s += softplusf(src[o * 32 + i]);
        float inv = 1.f / s;
        for (int i = 0; i < 32; ++i) {
            float v = softplusf(src[o * 32 + i]) * inv;
            if (tid < 32) s_wcd[o][i] = v; else s_wce[o][i] = v;
        }
    }
    if (tid < 32) {
        int i = tid;
        float c0[3], c1[3]; float s = 0.f;
        for (int h = 0; h < 3; ++h) {
            c0[h] = softplusf(Wsd[(i * 3 + h) * 2 + 0]);
            c1[h] = softplusf(Wsd[(i * 3 + h) * 2 + 1]);
            s += 2.f * c0[h] + c1[h];
        }
        float inv = 1.f / s;
        for (int h = 0; h < 3; ++h) {
            s_wsd[i][h * 3 + 0] = c0[h] * inv;
            s_wsd[i][h * 3 + 1] = c1[h] * inv;
            s_wsd[i][h * 3 + 2] = c0[h] * inv;
        }
    }
    if (tid < 128) {
        int i = tid >> 2, d = tid & 3;
        float v[9];
        for (int h = 0; h < 3; ++h)
            for (int w = 0; w < 3; ++w) {
                float val;
                if (d == 0)      val = softplusf(Wse0[(i * 3 + h) * 3 + w]);
                else if (d == 1) val = softplusf(Wse1[(i * 3 + h) * 2 + (w == 1 ? 1 : 0)]);
                else if (d == 2) val = softplusf(Wse0[(i * 3 + h) * 3 + (2 - w)]);
                else             val = softplusf(Wse3[(i * 3 + h) * 2 + (w == 1 ? 1 : 0)]);
                v[h * 3 + w] = val;
            }
        float s = 0.f;
        for (int k = 0; k < 9; ++k) s += v[k];
        float inv = 1.f / s;
        for (int k = 0; k < 9; ++k) s_wse[i][d][k] = v[k] * inv;
    }
    if (tid < 128) {
        int p = tid >> 5, i = tid & 31;
        const int jmap[4][4] = {{0,1,2,3},{4,5,4,6},{2,1,0,3},{7,8,7,9}};
        float v[4]; float s = 0.f;
        for (int d = 0; d < 4; ++d) { v[d] = softplusf(Wdir[i * 10 + jmap[p][d]]); s += v[d]; }
        float inv = 1.f / s;
        for (int d = 0; d < 4; ++d) s_wdir[p][i][d] = v[d] * inv;
    }
    if (tid < 32) {
        int i = tid;
        float p0 = softplusf(Wpow[i*5+0]), p1 = softplusf(Wpow[i*5+1]), p2 = softplusf(Wpow[i*5+2]);
        float p3 = softplusf(Wpow[i*5+3]), p4 = softplusf(Wpow[i*5+4]);
        float* wp = (float*)(wsb + OFFB_WPOW) + (size_t)i * 8;
        wp[0]=p0; wp[1]=p2; wp[2]=p1; wp[3]=p4;   // s=0 (fwd)
        wp[4]=p1; wp[5]=p3; wp[6]=p0; wp[7]=p4;   // s=1 (bwd)
        float c0 = sigmf(Wprop[i*3+0]), c1 = sigmf(Wprop[i*3+1]), c2 = sigmf(Wprop[i*3+2]);
        float* pr = (float*)(wsb + OFFB_WPROP) + (size_t)i * 4;
        pr[0]=c1; pr[1]=c0; pr[2]=c1; pr[3]=c2;
    }
    __syncthreads();

    const int gtid = (int)blockIdx.x * 256 + tid;
    const int gstr = (int)(gridDim.x * blockDim.x);
    // conv_d weights in A-fragment bf16 layout: wdf[((tap*4+quad)*32+oc)*8+j], ic=quad*8+j
    unsigned short* wdf = (unsigned short*)(wsb + OFFB_WDFRAG);
    for (int g = gtid; g < 9 * 4 * 32; g += gstr) {
        int oc = g & 31, quad = (g >> 5) & 3, tap = g >> 7;
        unsigned int w[4];
        #pragma unroll
        for (int jp = 0; jp < 4; ++jp) {
            int i0 = quad * 8 + jp * 2;
            unsigned short lo = f2bf(s_wcd[oc][i0]     * s_wsd[i0][tap]);
            unsigned short hi = f2bf(s_wcd[oc][i0 + 1] * s_wsd[i0 + 1][tap]);
            w[jp] = (unsigned int)lo | ((unsigned int)hi << 16);
        }
        *(uint4*)(wdf + (size_t)g * 8) = make_uint4(w[0], w[1], w[2], w[3]);
    }
    // e-conv weights, bf16, A-fragment layout: wfrag[((tap*16+qq)*128+oc)*8+j]
    unsigned short* wfrag = (unsigned short*)(wsb + OFFB_WFRAG);
    for (int g = gtid; g < 9 * 16 * 128; g += gstr) {
        int oc = g & 127, qq = (g >> 7) & 15, tap = g >> 11;
        int o = oc >> 2, p = oc & 3;
        unsigned int w[4];
        #pragma unroll
        for (int jp = 0; jp < 4; ++jp) {
            int ic0 = qq * 8 + jp * 2;
            int i0 = ic0 >> 2, d0 = ic0 & 3;
            int i1 = (ic0 + 1) >> 2, d1 = (ic0 + 1) & 3;
            unsigned short lo = f2bf(s_wce[o][i0] * s_wdir[p][i0][d0] * s_wse[i0][d0][tap]);
            unsigned short hi = f2bf(s_wce[o][i1] * s_wdir[p][i1][d1] * s_wse[i1][d1][tap]);
            w[jp] = (unsigned int)lo | ((unsigned int)hi << 16);
        }
        *(uint4*)(wfrag + (size_t)g * 8) = make_uint4(w[0], w[1], w[2], w[3]);
    }
}

// -------------------------------------------------------------- ce/ece in ---
// r8 form (measured best): 2 px/thread, 128-thread blocks, vectorized float4
// stencil rows shared within the pixel pair; store phase via LDS replays the
// exact r2/r7 per-wave store pattern. Bit-identical outputs.
__global__ __launch_bounds__(128, 4) void prep_inputs(
    const float* __restrict__ xin, const float* __restrict__ ce,
    const float* __restrict__ ece, const char* __restrict__ wsb,
    unsigned short* __restrict__ ce_bf, unsigned short* __restrict__ ece_bf,
    unsigned short* __restrict__ x_bf)
{
    __shared__ unsigned short s_ce [64][4][8];   // 4 KB
    __shared__ unsigned short s_ece[64][4][8];   // 4 KB
    __shared__ unsigned short s_x[2][64][8];     // 2 KB

    const int tid = threadIdx.x;
    const int sp  = tid & 31;                // pair slot: px = 2sp, 2sp+1
    const int grp = tid >> 5;                // 0..3
    const int bx  = (int)blockIdx.x;
    const int xb  = bx * 64 + sp * 2;
    const int y   = (int)blockIdx.y;
    const int zz  = (int)blockIdx.z;         // b*4 + cb
    const int b   = zz >> 2;
    const int cb  = zz & 3;
    const int i0  = cb * 8 + grp * 2;        // channels i0, i0+1
    const float* wprop = (const float*)(wsb + OFFB_WPROP);
    const float* wpow  = (const float*)(wsb + OFFB_WPOW);
    const float LEPS = -66.43856f;           // log2(1e-20)

    // edge shift: left edge (xb==0) shifts window right by 1; right edge
    // (xb==190) shifts left by 1. val[j] covers x = xb-1+j, j=0..3.
    const int s  = (xb == 0) ? 1 : ((xb == 190) ? -1 : 0);
    const int xbase = xb - 1 + s;

    #pragma unroll
    for (int ii = 0; ii < 2; ++ii) {
        const int i = i0 + ii;
        const float* dcd = xin + ((size_t)(b * N + i)) * HW;
        const float* cd  = xin + ((size_t)((Bb + b) * N + i)) * HW;

        float cv[3][4], ld[3][4], dcent[2];
        #pragma unroll
        for (int r = 0; r < 3; ++r) {
            int yy = y + r - 1;
            f32x4 c4 = (f32x4){0.f, 0.f, 0.f, 0.f};
            f32x4 d4 = (f32x4){0.f, 0.f, 0.f, 0.f};
            if (yy >= 0 && yy < Hh) {                       // wave-uniform
                c4 = load4u(cd  + (size_t)yy * Ww + xbase);
                d4 = load4u(dcd + (size_t)yy * Ww + xbase);
            }
            #pragma unroll
            for (int j = 0; j < 4; ++j) {
                int xx = xb - 1 + j;
                bool vx = (xx >= 0) && (xx < Ww);
                int vi = (j - s) & 3;
                float c  = vx ? c4[vi] : 0.f;
                float dd = vx ? d4[vi] : 0.f;
                cv[r][j] = c;
                if (r == 1 && j >= 1 && j <= 2) dcent[j - 1] = dd;
                ld[r][j] = __builtin_amdgcn_logf(dd * frcp(c + EPSF) + EPSF);  // log2
            }
        }
        // x_bf center staging (raw values, as r7)
        #pragma unroll
        for (int k = 0; k < 2; ++k) {
            s_x[0][sp * 2 + k][grp * 2 + ii] = f2bf(dcent[k]);
            s_x[1][sp * 2 + k][grp * 2 + ii] = f2bf(cv[1][k + 1]);
        }
        #pragma unroll
        for (int d = 0; d < 4; ++d) {
            size_t idx = ((size_t)(b * 128 + i * 4 + d)) * HW + (size_t)y * Ww + xb;
            float2 c2 = *(const float2*)(ce + idx);
            float2 e2 = *(const float2*)(ece + idx);
            float p0 = wpow[i * 8 + d], p1 = wpow[i * 8 + 4 + d];
            float wp = wprop[i * 4 + d];
            #pragma unroll
            for (int k = 0; k < 2; ++k) {
                float lr, cn;
                if (d == 0)      { lr = ld[0][k]     - ld[2][k + 2]; cn = cv[0][k]     * cv[2][k + 2]; }
                else if (d == 1) { lr = ld[0][k + 1] - ld[2][k + 1]; cn = cv[0][k + 1] * cv[2][k + 1]; }
                else if (d == 2) { lr = ld[0][k + 2] - ld[2][k];     cn = cv[0][k + 2] * cv[2][k];     }
                else             { lr = ld[1][k + 2] - ld[1][k];     cn = cv[1][k + 2] * cv[1][k];     }
                float lrf = fmaxf(fminf(lr, 0.f), LEPS);    // == log2(clip(rf,EPS,1))
                float lrb = fmaxf(fminf(-lr, 0.f), LEPS);
                float ef = __builtin_amdgcn_exp2f(p0 * lrf);
                float eb = __builtin_amdgcn_exp2f(p1 * lrb);
                float en = fminf(ef, eb);
                float cr = (k == 0) ? c2.x : c2.y;
                float er = (k == 0) ? e2.x : e2.y;
                s_ce [sp * 2 + k][grp][ii * 4 + d] = f2bf(cr * wp + cn * (1.f - wp));
                s_ece[sp * 2 + k][grp][ii * 4 + d] = f2bf(er * wp + en * cn * (1.f - wp));
            }
        }
    }
    __syncthreads();
    // ce/ece stores: identical per-wave pattern to r2/r7 (64 consecutive px,
    // one uint4 at 256B stride per (grp,arr))
    #pragma unroll
    for (int it = 0; it < 4; ++it) {
        int flat = it * 128 + tid;           // 0..511
        int arr  = flat >> 8;
        int g    = (flat >> 6) & 3;
        int px   = flat & 63;
        size_t base = ((size_t)b * HW + (size_t)y * Ww + (size_t)bx * 64 + px) * 128
                      + (size_t)(cb * 8 + g * 2) * 4;
        const unsigned short* srcp = arr ? &s_ece[px][g][0] : &s_ce[px][g][0];
        *(uint4*)((arr ? ece_bf : ce_bf) + base) = *(const uint4*)srcp;
    }
    // x_bf: dense 16B-record stores into the (b,cb,t) planes (as r7)
    if (tid < 128) {
        int t = tid & 1, p = tid >> 1;
        size_t plane = (size_t)(b * 4 + cb) * 2 + t;
        size_t a = (plane * HW + (size_t)y * Ww + (size_t)bx * 64 + p) * 8;
        *(uint4*)(x_bf + a) = *(const uint4*)&s_x[t][p][0];
    }
}

// ------------------------------------------- 128->128 3x3 conv via MFMA -----
// r9: one 512-thread block per (tile, b) stages BOTH ce and ece tiles in a
// single phase (5760 gload_lds into one linear 92KB LDS range -> wave-uniform
// base + lane*16 holds even at the buffer seam), ONE barrier, then waves 0-3
// compute ce while waves 4-7 compute ece. Halves stage-phases and barrier
// drains per tile vs r4; MFMA order/inputs/stores bit-identical.
__global__ __launch_bounds__(512, 2) void conv_e_mfma(
    const unsigned short* __restrict__ ce_bf, const unsigned short* __restrict__ ece_bf,
    const unsigned short* __restrict__ wfrag,
    float* __restrict__ ce_out, float* __restrict__ ece_out)
{
    const int b = blockIdx.z;                     // 0..1
    __shared__ unsigned short tile[2][180 * 128]; // 92160 B, linear across both

    const int tid  = threadIdx.x;                 // 0..511
    const int lane = tid & 63;
    const int l16  = lane & 15;
    const int quad = lane >> 4;
    const int wave = tid >> 6;                    // 0..7
    const int t    = wave >> 2;                   // 0: ce, 1: ece
    const int sub  = wave & 3;
    const int ph   = sub >> 1;                    // pixel-row half
    const int woc  = (sub & 1) * 64;              // oc half
    const int x0 = ((int)blockIdx.x % 12) * 16;
    const int y0 = ((int)blockIdx.x / 12) * 8;

    const unsigned short* base0 = ce_bf  + (size_t)b * HW * 128;
    const unsigned short* base1 = ece_bf + (size_t)b * HW * 128;

    const bool interior = (x0 >= 16 && x0 <= 160 && y0 >= 8 && y0 <= 176);
    if (interior) {
        #pragma unroll
        for (int it = 0; it < 12; ++it) {
            int idx = it * 512 + tid;
            if (idx < 2 * 2880) {
                int which = idx >= 2880;
                int r = idx - which * 2880;
                int p = r >> 4, slot = r & 15;
                int hy = p / 18, hx = p - hy * 18;
                int gy = y0 + hy - 1, gx = x0 + hx - 1;
                int csrc = slot ^ (p & 7);
                const unsigned short* src = which ? base1 : base0;
                gload_lds16((const char*)src + ((size_t)(gy * Ww + gx) * 16 + csrc) * 16,
                            (char*)tile + (size_t)idx * 16);
            }
        }
    } else {
        for (int idx = tid; idx < 2 * 2880; idx += 512) {
            int which = idx >= 2880;
            int r = idx - which * 2880;
            int p = r >> 4, slot = r & 15;
            int hy = p / 18, hx = p - hy * 18;
            int gy = y0 + hy - 1, gx = x0 + hx - 1;
            int csrc = slot ^ (p & 7);
            const uint4* gsrc = (const uint4*)(which ? base1 : base0);
            uint4 v = make_uint4(0u, 0u, 0u, 0u);
            if (gy >= 0 && gy < Hh && gx >= 0 && gx < Ww)
                v = gsrc[(size_t)(gy * Ww + gx) * 16 + csrc];
            *(uint4*)((unsigned short*)tile + (size_t)idx * 8) = v;
        }
    }
    __syncthreads();

    const unsigned short* tl = (const unsigned short*)tile + (size_t)t * (180 * 128);
    float* outp = t ? ece_out : ce_out;

    f32x4 acc[4][4];   // [mt][nt]
    #pragma unroll
    for (int mt = 0; mt < 4; ++mt)
        #pragma unroll
        for (int nt = 0; nt < 4; ++nt) acc[mt][nt] = (f32x4){0.f, 0.f, 0.f, 0.f};

    for (int tap = 0; tap < 9; ++tap) {
        const int ky = tap / 3, kx = tap - ky * 3;
        #pragma unroll
        for (int q = 0; q < 4; ++q) {
            const int cq = q * 4 + quad;
            const unsigned short* wb = wfrag + (size_t)((tap * 16 + cq) * 128) * 8;
            bf16x8 a[4];
            #pragma unroll
            for (int mt = 0; mt < 4; ++mt)
                a[mt] = *(const bf16x8*)(wb + (size_t)(woc + mt * 16 + l16) * 8);
            #pragma unroll
            for (int nt = 0; nt < 4; ++nt) {
                int px = (ph * 4 + nt + ky) * 18 + l16 + kx;
                bf16x8 bv = *(const bf16x8*)&tl[px * 128 + ((cq ^ (px & 7)) << 3)];
                #pragma unroll
                for (int mt = 0; mt < 4; ++mt)
                    acc[mt][nt] = __builtin_amdgcn_mfma_f32_16x16x32_bf16(a[mt], bv, acc[mt][nt], 0, 0, 0);
            }
        }
    }

    #pragma unroll
    for (int mt = 0; mt < 4; ++mt)
        #pragma unroll
        for (int nt = 0; nt < 4; ++nt) {
            int y = y0 + ph * 4 + nt, x = x0 + l16;
            #pragma unroll
            for (int r = 0; r < 4; ++r) {
                int oc = woc + mt * 16 + quad * 4 + r;
                outp[((size_t)b * 128 + oc) * HW + (size_t)y * Ww + x] = acc[mt][nt][r];
            }
        }
}

// ----------------------- gated 32->32 conv via MFMA (dcd_out & cd_out) ------
// x-tile staged from x_bf planes (16B/pixel, fully dense reads) via
// global_load_lds + chunk-XOR swizzle. E path unchanged (bit-identical).
__global__ __launch_bounds__(256) void conv_d_mfma(
    const unsigned short* __restrict__ x_bf, const unsigned short* __restrict__ wdfrag,
    const float* __restrict__ ece_out, const float* __restrict__ ce_out,
    float* __restrict__ out0)
{
    const int b = blockIdx.y;
    __shared__ unsigned short xt[108 * 64];      // 13824 B ([hp][t*32+i], XOR-swizzled)
    __shared__ unsigned short Ebf[4 * 64 * 40];  // 20480 B

    const int tid  = threadIdx.x;
    const int lane = tid & 63;
    const int l16  = lane & 15;
    const int quad = lane >> 4;
    const int wave = tid >> 6;
    const int t    = wave >> 1;      // 0: dcd, 1: cd
    const int nh   = wave & 1;       // pixel half
    const int x0 = ((int)blockIdx.x % 12) * 16;
    const int y0 = ((int)blockIdx.x / 12) * 4;

    const bool interior = (x0 >= 16 && x0 <= 160 && y0 >= 4 && y0 <= 184);
    if (interior) {
        #pragma unroll
        for (int it = 0; it < 4; ++it) {
            int idx = it * 256 + tid;
            if (idx < 108 * 8) {
                int hp = idx >> 3, slot = idx & 7;
                int hy = hp / 18, hx = hp - hy * 18;
                int gy = y0 + hy - 1, gx = x0 + hx - 1;
                int csrc = slot ^ (hp & 7);
                size_t splane = (size_t)(b * 4 + (csrc & 3)) * 2 + (csrc >> 2);
                gload_lds16((const char*)x_bf + (splane * HW + (size_t)(gy * Ww + gx)) * 16,
                            (char*)xt + (size_t)idx * 16);
            }
        }
    } else {
        const uint4* gsrc = (const uint4*)x_bf;
        for (int idx = tid; idx < 108 * 8; idx += 256) {
            int hp = idx >> 3, slot = idx & 7;
            int hy = hp / 18, hx = hp - hy * 18;
            int gy = y0 + hy - 1, gx = x0 + hx - 1;
            int csrc = slot ^ (hp & 7);
            size_t splane = (size_t)(b * 4 + (csrc & 3)) * 2 + (csrc >> 2);
            uint4 v = make_uint4(0u, 0u, 0u, 0u);
            if (gy >= 0 && gy < Hh && gx >= 0 && gx < Ww)
                v = gsrc[splane * HW + (size_t)(gy * Ww + gx)];
            *(uint4*)&xt[(size_t)idx * 8] = v;
        }
    }
    // stage E (fp32 reads + rcp + clamp + f2bf)
    for (int idx = tid; idx < 32 * 64; idx += 256) {
        int px = idx & 15, py = (idx >> 4) & 3, i = idx >> 6;
        size_t gp = (size_t)(y0 + py) * Ww + x0 + px;
        int p = py * 16 + px;
        #pragma unroll
        for (int d = 0; d < 4; ++d) {
            size_t eidx = ((size_t)(b * 128 + i * 4 + d)) * HW + gp;
            float e = fminf(fmaxf(ece_out[eidx] * frcp(ce_out[eidx] + EPSF), EPSF), 1.f);
            Ebf[(d * 64 + p) * 40 + i] = f2bf(e);
        }
    }
    __syncthreads();

    f32x4 acc[2][2];   // [ntile][mtile]
    #pragma unroll
    for (int nt = 0; nt < 2; ++nt)
        #pragma unroll
        for (int mt = 0; mt < 2; ++mt) acc[nt][mt] = (f32x4){0.f, 0.f, 0.f, 0.f};

    const int cxt = t * 4 + quad;                      // x-chunk for this thread
    const int dmap[9] = {0, 1, 2, 3, 0, 3, 2, 1, 0};   // index 4 unused
    #pragma unroll
    for (int tap = 0; tap < 9; ++tap) {
        const int ky = tap / 3, kx = tap % 3;
        bf16x8 a0 = *(const bf16x8*)(wdfrag + (size_t)(((tap * 4 + quad) * 32) + l16) * 8);
        bf16x8 a1 = *(const bf16x8*)(wdfrag + (size_t)(((tap * 4 + quad) * 32) + 16 + l16) * 8);
        #pragma unroll
        for (int nt = 0; nt < 2; ++nt) {
            int p = nh * 32 + nt * 16 + l16;
            int py = p >> 4, px = p & 15;
            int hp = (py + ky) * 18 + px + kx;
            bf16x8 xv = *(const bf16x8*)&xt[hp * 64 + ((cxt ^ (hp & 7)) << 3)];
            bf16x8 g;
            if (tap == 4) g = xv;
            else {
                bf16x8 ev = *(const bf16x8*)&Ebf[(dmap[tap] * 64 + p) * 40 + quad * 8];
                g = bfmul8(xv, ev);
            }
            acc[nt][0] = __builtin_amdgcn_mfma_f32_16x16x32_bf16(a0, g, acc[nt][0], 0, 0, 0);
            acc[nt][1] = __builtin_amdgcn_mfma_f32_16x16x32_bf16(a1, g, acc[nt][1], 0, 0, 0);
        }
    }

    #pragma unroll
    for (int nt = 0; nt < 2; ++nt) {
        int p = nh * 32 + nt * 16 + l16;
        int py = p >> 4, px = p & 15;
        size_t gp = (size_t)(y0 + py) * Ww + x0 + px;
        #pragma unroll
        for (int mt = 0; mt < 2; ++mt)
            #pragma unroll
            for (int r = 0; r < 4; ++r) {
                int oc = mt * 16 + quad * 4 + r;
                out0[((size_t)((t * Bb + b) * N + oc)) * HW + gp] = acc[nt][mt][r];
            }
    }
}

extern "C" void kernel_launch(void* const* d_in, const int* in_sizes, int n_in,
                              void* d_out, int out_size, void* d_ws, size_t ws_size,
                              hipStream_t stream)
{
    const float* x     = (const float*)d_in[0];
    const float* ece   = (const float*)d_in[1];
    const float* ce    = (const float*)d_in[2];
    const float* Wcd   = (const float*)d_in[3];
    const float* Wsd   = (const float*)d_in[4];
    const float* Wce   = (const float*)d_in[5];
    const float* Wse0  = (const float*)d_in[6];
    const float* Wse1  = (const float*)d_in[7];
    const float* Wse3  = (const float*)d_in[8];
    const float* Wdir  = (const float*)d_in[9];
    const float* Wpow  = (const float*)d_in[10];
    const float* Wprop = (const float*)d_in[11];
    float* out = (float*)d_out;
    char* wsb  = (char*)d_ws;

    unsigned short* ce_bf  = (unsigned short*)(wsb + OFFB_CE_BF);
    unsigned short* ece_bf = (unsigned short*)(wsb + OFFB_ECE_BF);
    unsigned short* x_bf   = (unsigned short*)(wsb + OFFB_X_BF);
    unsigned short* wfrag  = (unsigned short*)(wsb + OFFB_WFRAG);
    unsigned short* wdfrag = (unsigned short*)(wsb + OFFB_WDFRAG);
    float* out0    = out;
    float* ece_out = out + OUT0_SZ;
    float* ce_out  = out + OUT0_SZ + EOUT_SZ;

    prep_weights<<<32, 256, 0, stream>>>(Wcd, Wsd, Wce, Wse0, Wse1, Wse3, Wdir, Wpow, Wprop, wsb);
    prep_inputs<<<dim3(3, Hh, Bb * 4), 128, 0, stream>>>(x, ce, ece, wsb, ce_bf, ece_bf, x_bf);
    conv_e_mfma<<<dim3(288, 1, 2), 512, 0, stream>>>(ce_bf, ece_bf, wfrag, ce_out, ece_out);
    conv_d_mfma<<<dim3(576, Bb), 256, 0, stream>>>(x_bf, wdfrag, ece_out, ce_out, out0);
}

// Round 10
// 310.989 us; speedup vs baseline: 1.0406x; 1.0406x over previous
//
#include <hip/hip_runtime.h>
#include <math.h>

#define EPSF 1e-20f
static constexpr int N  = 32;
static constexpr int Hh = 192;
static constexpr int Ww = 192;
static constexpr int Bb = 2;
static constexpr int HW = Hh * Ww;            // 36864

// workspace layout (bytes)
static constexpr size_t OFFB_WDFRAG  = 0;          // 9*4*32*8 bf16     = 18432 B
static constexpr size_t OFFB_WPROP   = 36864;      // 32*4 fp32         = 512 B
static constexpr size_t OFFB_WPOW    = 37376;      // 32*8 fp32         = 1024 B
static constexpr size_t OFFB_WFRAG   = 40960;      // 9*16*128*8 bf16   = 294912 B
static constexpr size_t OFFB_CE_BF   = 335872;     // 2*HW*128 bf16     = 18874368 B
static constexpr size_t OFFB_ECE_BF  = OFFB_CE_BF + (size_t)2 * HW * 128 * 2;
static constexpr size_t OFFB_X_BF    = OFFB_ECE_BF + (size_t)2 * HW * 128 * 2;  // 16 planes x HW x 16B = 9.4 MB

static constexpr size_t OUT0_SZ  = (size_t)4 * N * HW;      // 4,718,592
static constexpr size_t EOUT_SZ  = (size_t)Bb * N * 4 * HW; // 9,437,184

typedef short bf16x8 __attribute__((ext_vector_type(8)));
typedef float f32x4  __attribute__((ext_vector_type(4)));

__device__ __forceinline__ float softplusf(float x) { return log1pf(expf(x)); }
__device__ __forceinline__ float sigmf(float x)     { return 1.f / (1.f + expf(-x)); }
__device__ __forceinline__ unsigned short f2bf(float f) {
    unsigned int u = __float_as_uint(f);
    u = (u + 0x7fffu + ((u >> 16) & 1u)) >> 16;   // RNE
    return (unsigned short)u;
}
__device__ __forceinline__ float frcp(float x) { return __builtin_amdgcn_rcpf(x); }
// unaligned-tolerant float4 load (4B-aligned ok)
__device__ __forceinline__ f32x4 load4u(const float* p) {
    f32x4 v; __builtin_memcpy(&v, p, 16); return v;
}
// packed bf16 elementwise multiply (round-half-up repack; inputs in [0,1])
__device__ __forceinline__ bf16x8 bfmul8(bf16x8 a, bf16x8 b) {
    union U { bf16x8 v; unsigned int u[4]; };
    U ua, ub, r; ua.v = a; ub.v = b;
    #pragma unroll
    for (int i = 0; i < 4; ++i) {
        float alo = __uint_as_float(ua.u[i] << 16);
        float ahi = __uint_as_float(ua.u[i] & 0xffff0000u);
        float blo = __uint_as_float(ub.u[i] << 16);
        float bhi = __uint_as_float(ub.u[i] & 0xffff0000u);
        unsigned int lo = __float_as_uint(alo * blo);
        unsigned int hi = __float_as_uint(ahi * bhi);
        lo = (lo + 0x8000u) >> 16;
        hi = (hi + 0x8000u) & 0xffff0000u;
        r.u[i] = hi | lo;
    }
    return r.v;
}

// direct global -> LDS, 16 bytes per lane (LDS dst must be base + lane*16)
typedef __attribute__((address_space(1))) unsigned int ga_u32;
typedef __attribute__((address_space(3))) unsigned int ls_u32;
__device__ __forceinline__ void gload_lds16(const void* g, void* l) {
    __builtin_amdgcn_global_load_lds((ga_u32*)g, (ls_u32*)l, 16, 0, 0);
}

// ---------------------------------------------------------------- weights ---
__global__ void prep_weights(const float* __restrict__ Wcd, const float* __restrict__ Wsd,
                             const float* __restrict__ Wce, const float* __restrict__ Wse0,
                             const float* __restrict__ Wse1, const float* __restrict__ Wse3,
                             const float* __restrict__ Wdir, const float* __restrict__ Wpow,
                             const float* __restrict__ Wprop, char* __restrict__ wsb)
{
    __shared__ float s_wcd[32][32];
    __shared__ float s_wce[32][32];
    __shared__ float s_wsd[32][9];
    __shared__ float s_wse[32][4][9];
    __shared__ float s_wdir[4][32][4];
    const int tid = threadIdx.x;

    if (tid < 64) {
        int o = tid & 31;
        const float* src = (tid < 32) ? Wcd : Wce;
        float s = 0.f;
        for (int i = 0; i < 32; ++i) s += softplusf(src[o * 32 + i]);
        float inv = 1.f / s;
        for (int i = 0; i < 32; ++i) {
            float v = softplusf(src[o * 32 + i]) * inv;
            if (tid < 32) s_wcd[o][i] = v; else s_wce[o][i] = v;
        }
    }
    if (tid < 32) {
        int i = tid;
        float c0[3], c1[3]; float s = 0.f;
        for (int h = 0; h < 3; ++h) {
            c0[h] = softplusf(Wsd[(i * 3 + h) * 2 + 0]);
            c1[h] = softplusf(Wsd[(i * 3 + h) * 2 + 1]);
            s += 2.f * c0[h] + c1[h];
        }
        float inv = 1.f / s;
        for (int h = 0; h < 3; ++h) {
            s_wsd[i][h * 3 + 0] = c0[h] * inv;
            s_wsd[i][h * 3 + 1] = c1[h] * inv;
            s_wsd[i][h * 3 + 2] = c0[h] * inv;
        }
    }
    if (tid < 128) {
        int i = tid >> 2, d = tid & 3;
        float v[9];
        for (int h = 0; h < 3; ++h)
            for (int w = 0; w < 3; ++w) {
                float val;
                if (d == 0)      val = softplusf(Wse0[(i * 3 + h) * 3 + w]);
                else if (d == 1) val = softplusf(Wse1[(i * 3 + h) * 2 + (w == 1 ? 1 : 0)]);
                else if (d == 2) val = softplusf(Wse0[(i * 3 + h) * 3 + (2 - w)]);
                else             val = softplusf(Wse3[(i * 3 + h) * 2 + (w == 1 ? 1 : 0)]);
                v[h * 3 + w] = val;
            }
        float s = 0.f;
        for (int k = 0; k < 9; ++k) s += v[k];
        float inv = 1.f / s;
        for (int k = 0; k < 9; ++k) s_wse[i][d][k] = v[k] * inv;
    }
    if (tid < 128) {
        int p = tid >> 5, i = tid & 31;
        const int jmap[4][4] = {{0,1,2,3},{4,5,4,6},{2,1,0,3},{7,8,7,9}};
        float v[4]; float s = 0.f;
        for (int d = 0; d < 4; ++d) { v[d] = softplusf(Wdir[i * 10 + jmap[p][d]]); s += v[d]; }
        float inv = 1.f / s;
        for (int d = 0; d < 4; ++d) s_wdir[p][i][d] = v[d] * inv;
    }
    if (tid < 32) {
        int i = tid;
        float p0 = softplusf(Wpow[i*5+0]), p1 = softplusf(Wpow[i*5+1]), p2 = softplusf(Wpow[i*5+2]);
        float p3 = softplusf(Wpow[i*5+3]), p4 = softplusf(Wpow[i*5+4]);
        float* wp = (float*)(wsb + OFFB_WPOW) + (size_t)i * 8;
        wp[0]=p0; wp[1]=p2; wp[2]=p1; wp[3]=p4;   // s=0 (fwd)
        wp[4]=p1; wp[5]=p3; wp[6]=p0; wp[7]=p4;   // s=1 (bwd)
        float c0 = sigmf(Wprop[i*3+0]), c1 = sigmf(Wprop[i*3+1]), c2 = sigmf(Wprop[i*3+2]);
        float* pr = (float*)(wsb + OFFB_WPROP) + (size_t)i * 4;
        pr[0]=c1; pr[1]=c0; pr[2]=c1; pr[3]=c2;
    }
    __syncthreads();

    const int gtid = (int)blockIdx.x * 256 + tid;
    const int gstr = (int)(gridDim.x * blockDim.x);
    // conv_d weights in A-fragment bf16 layout: wdf[((tap*4+quad)*32+oc)*8+j], ic=quad*8+j
    unsigned short* wdf = (unsigned short*)(wsb + OFFB_WDFRAG);
    for (int g = gtid; g < 9 * 4 * 32; g += gstr) {
        int oc = g & 31, quad = (g >> 5) & 3, tap = g >> 7;
        unsigned int w[4];
        #pragma unroll
        for (int jp = 0; jp < 4; ++jp) {
            int i0 = quad * 8 + jp * 2;
            unsigned short lo = f2bf(s_wcd[oc][i0]     * s_wsd[i0][tap]);
            unsigned short hi = f2bf(s_wcd[oc][i0 + 1] * s_wsd[i0 + 1][tap]);
            w[jp] = (unsigned int)lo | ((unsigned int)hi << 16);
        }
        *(uint4*)(wdf + (size_t)g * 8) = make_uint4(w[0], w[1], w[2], w[3]);
    }
    // e-conv weights, bf16, A-fragment layout: wfrag[((tap*16+qq)*128+oc)*8+j]
    unsigned short* wfrag = (unsigned short*)(wsb + OFFB_WFRAG);
    for (int g = gtid; g < 9 * 16 * 128; g += gstr) {
        int oc = g & 127, qq = (g >> 7) & 15, tap = g >> 11;
        int o = oc >> 2, p = oc & 3;
        unsigned int w[4];
        #pragma unroll
        for (int jp = 0; jp < 4; ++jp) {
            int ic0 = qq * 8 + jp * 2;
            int i0 = ic0 >> 2, d0 = ic0 & 3;
            int i1 = (ic0 + 1) >> 2, d1 = (ic0 + 1) & 3;
            unsigned short lo = f2bf(s_wce[o][i0] * s_wdir[p][i0][d0] * s_wse[i0][d0][tap]);
            unsigned short hi = f2bf(s_wce[o][i1] * s_wdir[p][i1][d1] * s_wse[i1][d1][tap]);
            w[jp] = (unsigned int)lo | ((unsigned int)hi << 16);
        }
        *(uint4*)(wfrag + (size_t)g * 8) = make_uint4(w[0], w[1], w[2], w[3]);
    }
}

// -------------------------------------------------------------- ce/ece in ---
// r10: TWO adjacent rows (y0, y0+1) per block. The 4 stencil row-loads per
// (ch,array) serve both output rows (vs 6 for separate blocks); 16 logs/ch
// (vs 24); 2x independent loads in flight. Store phase replays the exact
// r2/r7/r8 per-wave pattern once per row -> write-amp profile unchanged.
// Identical arithmetic per output -> bit-identical results.
__global__ __launch_bounds__(128, 4) void prep_inputs(
    const float* __restrict__ xin, const float* __restrict__ ce,
    const float* __restrict__ ece, const char* __restrict__ wsb,
    unsigned short* __restrict__ ce_bf, unsigned short* __restrict__ ece_bf,
    unsigned short* __restrict__ x_bf)
{
    __shared__ unsigned short s_ce [2][64][4][8];   // 8 KB
    __shared__ unsigned short s_ece[2][64][4][8];   // 8 KB
    __shared__ unsigned short s_x[2][2][64][8];     // 4 KB  [row][t][px][ch8]

    const int tid = threadIdx.x;
    const int sp  = tid & 31;                // pair slot: px = 2sp, 2sp+1
    const int grp = tid >> 5;                // 0..3
    const int bx  = (int)blockIdx.x;
    const int xb  = bx * 64 + sp * 2;
    const int y0  = (int)blockIdx.y * 2;     // rows y0, y0+1
    const int zz  = (int)blockIdx.z;         // b*4 + cb
    const int b   = zz >> 2;
    const int cb  = zz & 3;
    const int i0  = cb * 8 + grp * 2;        // channels i0, i0+1
    const float* wprop = (const float*)(wsb + OFFB_WPROP);
    const float* wpow  = (const float*)(wsb + OFFB_WPOW);
    const float LEPS = -66.43856f;           // log2(1e-20)

    // edge shift: left edge (xb==0) shifts window right by 1; right edge
    // (xb==190) shifts left by 1. val[j] covers x = xb-1+j, j=0..3.
    const int s  = (xb == 0) ? 1 : ((xb == 190) ? -1 : 0);
    const int xbase = xb - 1 + s;

    #pragma unroll
    for (int ii = 0; ii < 2; ++ii) {
        const int i = i0 + ii;
        const float* dcd = xin + ((size_t)(b * N + i)) * HW;
        const float* cd  = xin + ((size_t)((Bb + b) * N + i)) * HW;

        float cv[4][4], ld[4][4], dc[2][2];
        #pragma unroll
        for (int r = 0; r < 4; ++r) {
            int yy = y0 + r - 1;
            f32x4 c4 = (f32x4){0.f, 0.f, 0.f, 0.f};
            f32x4 d4 = (f32x4){0.f, 0.f, 0.f, 0.f};
            if (yy >= 0 && yy < Hh) {                       // wave-uniform
                c4 = load4u(cd  + (size_t)yy * Ww + xbase);
                d4 = load4u(dcd + (size_t)yy * Ww + xbase);
            }
            #pragma unroll
            for (int j = 0; j < 4; ++j) {
                int xx = xb - 1 + j;
                bool vx = (xx >= 0) && (xx < Ww);
                int vi = (j - s) & 3;
                float c  = vx ? c4[vi] : 0.f;
                float dd = vx ? d4[vi] : 0.f;
                cv[r][j] = c;
                if (r >= 1 && r <= 2 && j >= 1 && j <= 2) dc[r - 1][j - 1] = dd;
                ld[r][j] = __builtin_amdgcn_logf(dd * frcp(c + EPSF) + EPSF);  // log2
            }
        }
        // x_bf center staging (raw values): row rr center = window row rr+1
        #pragma unroll
        for (int rr = 0; rr < 2; ++rr)
            #pragma unroll
            for (int k = 0; k < 2; ++k) {
                s_x[rr][0][sp * 2 + k][grp * 2 + ii] = f2bf(dc[rr][k]);
                s_x[rr][1][sp * 2 + k][grp * 2 + ii] = f2bf(cv[rr + 1][k + 1]);
            }
        #pragma unroll
        for (int rr = 0; rr < 2; ++rr) {
            #pragma unroll
            for (int d = 0; d < 4; ++d) {
                size_t idx = ((size_t)(b * 128 + i * 4 + d)) * HW + (size_t)(y0 + rr) * Ww + xb;
                float2 c2 = *(const float2*)(ce + idx);
                float2 e2 = *(const float2*)(ece + idx);
                float p0 = wpow[i * 8 + d], p1 = wpow[i * 8 + 4 + d];
                float wp = wprop[i * 4 + d];
                #pragma unroll
                for (int k = 0; k < 2; ++k) {
                    float lr, cn;
                    if (d == 0)      { lr = ld[rr][k]     - ld[rr + 2][k + 2]; cn = cv[rr][k]     * cv[rr + 2][k + 2]; }
                    else if (d == 1) { lr = ld[rr][k + 1] - ld[rr + 2][k + 1]; cn = cv[rr][k + 1] * cv[rr + 2][k + 1]; }
                    else if (d == 2) { lr = ld[rr][k + 2] - ld[rr + 2][k];     cn = cv[rr][k + 2] * cv[rr + 2][k];     }
                    else             { lr = ld[rr + 1][k + 2] - ld[rr + 1][k]; cn = cv[rr + 1][k + 2] * cv[rr + 1][k]; }
                    float lrf = fmaxf(fminf(lr, 0.f), LEPS);    // == log2(clip(rf,EPS,1))
                    float lrb = fmaxf(fminf(-lr, 0.f), LEPS);
                    float ef = __builtin_amdgcn_exp2f(p0 * lrf);
                    float eb = __builtin_amdgcn_exp2f(p1 * lrb);
                    float en = fminf(ef, eb);
                    float cr = (k == 0) ? c2.x : c2.y;
                    float er = (k == 0) ? e2.x : e2.y;
                    s_ce [rr][sp * 2 + k][grp][ii * 4 + d] = f2bf(cr * wp + cn * (1.f - wp));
                    s_ece[rr][sp * 2 + k][grp][ii * 4 + d] = f2bf(er * wp + en * cn * (1.f - wp));
                }
            }
        }
    }
    __syncthreads();
    // ce/ece stores: exact r8 per-wave pattern, replayed per row
    #pragma unroll
    for (int rr = 0; rr < 2; ++rr) {
        #pragma unroll
        for (int it = 0; it < 4; ++it) {
            int flat = it * 128 + tid;           // 0..511
            int arr  = flat >> 8;
            int g    = (flat >> 6) & 3;
            int px   = flat & 63;
            size_t base = ((size_t)b * HW + (size_t)(y0 + rr) * Ww + (size_t)bx * 64 + px) * 128
                          + (size_t)(cb * 8 + g * 2) * 4;
            const unsigned short* srcp = arr ? &s_ece[rr][px][g][0] : &s_ce[rr][px][g][0];
            *(uint4*)((arr ? ece_bf : ce_bf) + base) = *(const uint4*)srcp;
        }
    }
    // x_bf: dense 16B-record stores into the (b,cb,t) planes, per row
    if (tid < 128) {
        int t = tid & 1, p = tid >> 1;
        size_t plane = (size_t)(b * 4 + cb) * 2 + t;
        #pragma unroll
        for (int rr = 0; rr < 2; ++rr) {
            size_t a = (plane * HW + (size_t)(y0 + rr) * Ww + (size_t)bx * 64 + p) * 8;
            *(uint4*)(x_bf + a) = *(const uint4*)&s_x[rr][t][p][0];
        }
    }
}

// ------------------------------------------- 128->128 3x3 conv via MFMA -----
// r8 form (measured local optimum — r5 fusion and r9 512-thr merge both lost
// to reduced block residency): 16x8 px tile, 128 oc/block, z=4 (t,b); per
// wave 64oc x 64px. Linear LDS + chunk XOR swizzle, global_load_lds staging.
__global__ __launch_bounds__(256, 3) void conv_e_mfma(
    const unsigned short* __restrict__ ce_bf, const unsigned short* __restrict__ ece_bf,
    const unsigned short* __restrict__ wfrag,
    float* __restrict__ ce_out, float* __restrict__ ece_out)
{
    const int z = blockIdx.z; const int t = z >> 1; const int b = z & 1;
    const unsigned short* in_bf = (t ? ece_bf : ce_bf) + (size_t)b * HW * 128;
    float* outp = t ? ece_out : ce_out;

    __shared__ unsigned short tile[180 * 128];   // 46080 B

    const int tid  = threadIdx.x;
    const int lane = tid & 63;
    const int l16  = lane & 15;
    const int quad = lane >> 4;
    const int wave = tid >> 6;
    const int ph   = wave >> 1;          // pixel-row half (rows 0-3 / 4-7)
    const int woc  = (wave & 1) * 64;    // oc half
    const int x0 = ((int)blockIdx.x % 12) * 16;
    const int y0 = ((int)blockIdx.x / 12) * 8;

    const bool interior = (x0 >= 16 && x0 <= 160 && y0 >= 8 && y0 <= 176);
    if (interior) {
        #pragma unroll
        for (int it = 0; it < 12; ++it) {
            int idx = it * 256 + tid;
            if (idx < 180 * 16) {
                int p = idx >> 4, slot = idx & 15;
                int hy = p / 18, hx = p - hy * 18;
                int gy = y0 + hy - 1, gx = x0 + hx - 1;
                int csrc = slot ^ (p & 7);
                gload_lds16((const char*)in_bf + ((size_t)(gy * Ww + gx) * 16 + csrc) * 16,
                            (char*)tile + (size_t)idx * 16);
            }
        }
    } else {
        const uint4* gsrc = (const uint4*)in_bf;
        for (int idx = tid; idx < 180 * 16; idx += 256) {
            int p = idx >> 4, slot = idx & 15;
            int hy = p / 18, hx = p - hy * 18;
            int gy = y0 + hy - 1, gx = x0 + hx - 1;
            int csrc = slot ^ (p & 7);
            uint4 v = make_uint4(0u, 0u, 0u, 0u);
            if (gy >= 0 && gy < Hh && gx >= 0 && gx < Ww)
                v = gsrc[(size_t)(gy * Ww + gx) * 16 + csrc];
            *(uint4*)&tile[(size_t)idx * 8] = v;
        }
    }
    __syncthreads();

    f32x4 acc[4][4];   // [mt][nt]
    #pragma unroll
    for (int mt = 0; mt < 4; ++mt)
        #pragma unroll
        for (int nt = 0; nt < 4; ++nt) acc[mt][nt] = (f32x4){0.f, 0.f, 0.f, 0.f};

    for (int tap = 0; tap < 9; ++tap) {
        const int ky = tap / 3, kx = tap - ky * 3;
        #pragma unroll
        for (int q = 0; q < 4; ++q) {
            const int cq = q * 4 + quad;
            const unsigned short* wb = wfrag + (size_t)((tap * 16 + cq) * 128) * 8;
            bf16x8 a[4];
            #pragma unroll
            for (int mt = 0; mt < 4; ++mt)
                a[mt] = *(const bf16x8*)(wb + (size_t)(woc + mt * 16 + l16) * 8);
            #pragma unroll
            for (int nt = 0; nt < 4; ++nt) {
                int px = (ph * 4 + nt + ky) * 18 + l16 + kx;
                bf16x8 bv = *(const bf16x8*)&tile[px * 128 + ((cq ^ (px & 7)) << 3)];
                #pragma unroll
                for (int mt = 0; mt < 4; ++mt)
                    acc[mt][nt] = __builtin_amdgcn_mfma_f32_16x16x32_bf16(a[mt], bv, acc[mt][nt], 0, 0, 0);
            }
        }
    }

    #pragma unroll
    for (int mt = 0; mt < 4; ++mt)
        #pragma unroll
        for (int nt = 0; nt < 4; ++nt) {
            int y = y0 + ph * 4 + nt, x = x0 + l16;
            #pragma unroll
            for (int r = 0; r < 4; ++r) {
                int oc = woc + mt * 16 + quad * 4 + r;
                outp[((size_t)b * 128 + oc) * HW + (size_t)y * Ww + x] = acc[mt][nt][r];
            }
        }
}

// ----------------------- gated 32->32 conv via MFMA (dcd_out & cd_out) ------
// x-tile staged from x_bf planes (16B/pixel, fully dense reads) via
// global_load_lds + chunk-XOR swizzle. E path unchanged (bit-identical).
__global__ __launch_bounds__(256) void conv_d_mfma(
    const unsigned short* __restrict__ x_bf, const unsigned short* __restrict__ wdfrag,
    const float* __restrict__ ece_out, const float* __restrict__ ce_out,
    float* __restrict__ out0)
{
    const int b = blockIdx.y;
    __shared__ unsigned short xt[108 * 64];      // 13824 B ([hp][t*32+i], XOR-swizzled)
    __shared__ unsigned short Ebf[4 * 64 * 40];  // 20480 B

    const int tid  = threadIdx.x;
    const int lane = tid & 63;
    const int l16  = lane & 15;
    const int quad = lane >> 4;
    const int wave = tid >> 6;
    const int t    = wave >> 1;      // 0: dcd, 1: cd
    const int nh   = wave & 1;       // pixel half
    const int x0 = ((int)blockIdx.x % 12) * 16;
    const int y0 = ((int)blockIdx.x / 12) * 4;

    const bool interior = (x0 >= 16 && x0 <= 160 && y0 >= 4 && y0 <= 184);
    if (interior) {
        #pragma unroll
        for (int it = 0; it < 4; ++it) {
            int idx = it * 256 + tid;
            if (idx < 108 * 8) {
                int hp = idx >> 3, slot = idx & 7;
                int hy = hp / 18, hx = hp - hy * 18;
                int gy = y0 + hy - 1, gx = x0 + hx - 1;
                int csrc = slot ^ (hp & 7);
                size_t splane = (size_t)(b * 4 + (csrc & 3)) * 2 + (csrc >> 2);
                gload_lds16((const char*)x_bf + (splane * HW + (size_t)(gy * Ww + gx)) * 16,
                            (char*)xt + (size_t)idx * 16);
            }
        }
    } else {
        const uint4* gsrc = (const uint4*)x_bf;
        for (int idx = tid; idx < 108 * 8; idx += 256) {
            int hp = idx >> 3, slot = idx & 7;
            int hy = hp / 18, hx = hp - hy * 18;
            int gy = y0 + hy - 1, gx = x0 + hx - 1;
            int csrc = slot ^ (hp & 7);
            size_t splane = (size_t)(b * 4 + (csrc & 3)) * 2 + (csrc >> 2);
            uint4 v = make_uint4(0u, 0u, 0u, 0u);
            if (gy >= 0 && gy < Hh && gx >= 0 && gx < Ww)
                v = gsrc[splane * HW + (size_t)(gy * Ww + gx)];
            *(uint4*)&xt[(size_t)idx * 8] = v;
        }
    }
    // stage E (fp32 reads + rcp + clamp + f2bf)
    for (int idx = tid; idx < 32 * 64; idx += 256) {
        int px = idx & 15, py = (idx >> 4) & 3, i = idx >> 6;
        size_t gp = (size_t)(y0 + py) * Ww + x0 + px;
        int p = py * 16 + px;
        #pragma unroll
        for (int d = 0; d < 4; ++d) {
            size_t eidx = ((size_t)(b * 128 + i * 4 + d)) * HW + gp;
            float e = fminf(fmaxf(ece_out[eidx] * frcp(ce_out[eidx] + EPSF), EPSF), 1.f);
            Ebf[(d * 64 + p) * 40 + i] = f2bf(e);
        }
    }
    __syncthreads();

    f32x4 acc[2][2];   // [ntile][mtile]
    #pragma unroll
    for (int nt = 0; nt < 2; ++nt)
        #pragma unroll
        for (int mt = 0; mt < 2; ++mt) acc[nt][mt] = (f32x4){0.f, 0.f, 0.f, 0.f};

    const int cxt = t * 4 + quad;                      // x-chunk for this thread
    const int dmap[9] = {0, 1, 2, 3, 0, 3, 2, 1, 0};   // index 4 unused
    #pragma unroll
    for (int tap = 0; tap < 9; ++tap) {
        const int ky = tap / 3, kx = tap % 3;
        bf16x8 a0 = *(const bf16x8*)(wdfrag + (size_t)(((tap * 4 + quad) * 32) + l16) * 8);
        bf16x8 a1 = *(const bf16x8*)(wdfrag + (size_t)(((tap * 4 + quad) * 32) + 16 + l16) * 8);
        #pragma unroll
        for (int nt = 0; nt < 2; ++nt) {
            int p = nh * 32 + nt * 16 + l16;
            int py = p >> 4, px = p & 15;
            int hp = (py + ky) * 18 + px + kx;
            bf16x8 xv = *(const bf16x8*)&xt[hp * 64 + ((cxt ^ (hp & 7)) << 3)];
            bf16x8 g;
            if (tap == 4) g = xv;
            else {
                bf16x8 ev = *(const bf16x8*)&Ebf[(dmap[tap] * 64 + p) * 40 + quad * 8];
                g = bfmul8(xv, ev);
            }
            acc[nt][0] = __builtin_amdgcn_mfma_f32_16x16x32_bf16(a0, g, acc[nt][0], 0, 0, 0);
            acc[nt][1] = __builtin_amdgcn_mfma_f32_16x16x32_bf16(a1, g, acc[nt][1], 0, 0, 0);
        }
    }

    #pragma unroll
    for (int nt = 0; nt < 2; ++nt) {
        int p = nh * 32 + nt * 16 + l16;
        int py = p >> 4, px = p & 15;
        size_t gp = (size_t)(y0 + py) * Ww + x0 + px;
        #pragma unroll
        for (int mt = 0; mt < 2; ++mt)
            #pragma unroll
            for (int r = 0; r < 4; ++r) {
                int oc = mt * 16 + quad * 4 + r;
                out0[((size_t)((t * Bb + b) * N + oc)) * HW + gp] = acc[nt][mt][r];
            }
    }
}

extern "C" void kernel_launch(void* const* d_in, const int* in_sizes, int n_in,
                              void* d_out, int out_size, void* d_ws, size_t ws_size,
                              hipStream_t stream)
{
    const float* x     = (const float*)d_in[0];
    const float* ece   = (const float*)d_in[1];
    const float* ce    = (const float*)d_in[2];
    const float* Wcd   = (const float*)d_in[3];
    const float* Wsd   = (const float*)d_in[4];
    const float* Wce   = (const float*)d_in[5];
    const float* Wse0  = (const float*)d_in[6];
    const float* Wse1  = (const float*)d_in[7];
    const float* Wse3  = (const float*)d_in[8];
    const float* Wdir  = (const float*)d_in[9];
    const float* Wpow  = (const float*)d_in[10];
    const float* Wprop = (const float*)d_in[11];
    float* out = (float*)d_out;
    char* wsb  = (char*)d_ws;

    unsigned short* ce_bf  = (unsigned short*)(wsb + OFFB_CE_BF);
    unsigned short* ece_bf = (unsigned short*)(wsb + OFFB_ECE_BF);
    unsigned short* x_bf   = (unsigned short*)(wsb + OFFB_X_BF);
    unsigned short* wfrag  = (unsigned short*)(wsb + OFFB_WFRAG);
    unsigned short* wdfrag = (unsigned short*)(wsb + OFFB_WDFRAG);
    float* out0    = out;
    float* ece_out = out + OUT0_SZ;
    float* ce_out  = out + OUT0_SZ + EOUT_SZ;

    prep_weights<<<32, 256, 0, stream>>>(Wcd, Wsd, Wce, Wse0, Wse1, Wse3, Wdir, Wpow, Wprop, wsb);
    prep_inputs<<<dim3(3, 96, Bb * 4), 128, 0, stream>>>(x, ce, ece, wsb, ce_bf, ece_bf, x_bf);
    conv_e_mfma<<<dim3(288, 1, 4), 256, 0, stream>>>(ce_bf, ece_bf, wfrag, ce_out, ece_out);
    conv_d_mfma<<<dim3(576, Bb), 256, 0, stream>>>(x_bf, wdfrag, ece_out, ce_out, out0);
}

// Round 11
// 293.171 us; speedup vs baseline: 1.1038x; 1.0608x over previous
//
#include <hip/hip_runtime.h>
#include <math.h>

#define EPSF 1e-20f
static constexpr int N  = 32;
static constexpr int Hh = 192;
static constexpr int Ww = 192;
static constexpr int Bb = 2;
static constexpr int HW = Hh * Ww;            // 36864

// workspace layout (bytes)
static constexpr size_t OFFB_WDFRAG  = 0;          // 9*4*32*8 bf16     = 18432 B
static constexpr size_t OFFB_WPROP   = 36864;      // 32*4 fp32         = 512 B
static constexpr size_t OFFB_WPOW    = 37376;      // 32*8 fp32         = 1024 B
static constexpr size_t OFFB_WFRAG   = 40960;      // 9*16*128*8 bf16   = 294912 B
static constexpr size_t OFFB_CE_BF   = 335872;     // 2*HW*128 bf16     = 18874368 B
static constexpr size_t OFFB_ECE_BF  = OFFB_CE_BF + (size_t)2 * HW * 128 * 2;
static constexpr size_t OFFB_X_BF    = OFFB_ECE_BF + (size_t)2 * HW * 128 * 2;  // 16 planes x HW x 16B = 9.4 MB

static constexpr size_t OUT0_SZ  = (size_t)4 * N * HW;      // 4,718,592
static constexpr size_t EOUT_SZ  = (size_t)Bb * N * 4 * HW; // 9,437,184

typedef short bf16x8 __attribute__((ext_vector_type(8)));
typedef float f32x4  __attribute__((ext_vector_type(4)));

__device__ __forceinline__ float softplusf(float x) { return log1pf(expf(x)); }
__device__ __forceinline__ float sigmf(float x)     { return 1.f / (1.f + expf(-x)); }
__device__ __forceinline__ unsigned short f2bf(float f) {
    unsigned int u = __float_as_uint(f);
    u = (u + 0x7fffu + ((u >> 16) & 1u)) >> 16;   // RNE
    return (unsigned short)u;
}
__device__ __forceinline__ float frcp(float x) { return __builtin_amdgcn_rcpf(x); }
// unaligned-tolerant float4 load (4B-aligned ok)
__device__ __forceinline__ f32x4 load4u(const float* p) {
    f32x4 v; __builtin_memcpy(&v, p, 16); return v;
}
// packed bf16 elementwise multiply (round-half-up repack; inputs in [0,1])
__device__ __forceinline__ bf16x8 bfmul8(bf16x8 a, bf16x8 b) {
    union U { bf16x8 v; unsigned int u[4]; };
    U ua, ub, r; ua.v = a; ub.v = b;
    #pragma unroll
    for (int i = 0; i < 4; ++i) {
        float alo = __uint_as_float(ua.u[i] << 16);
        float ahi = __uint_as_float(ua.u[i] & 0xffff0000u);
        float blo = __uint_as_float(ub.u[i] << 16);
        float bhi = __uint_as_float(ub.u[i] & 0xffff0000u);
        unsigned int lo = __float_as_uint(alo * blo);
        unsigned int hi = __float_as_uint(ahi * bhi);
        lo = (lo + 0x8000u) >> 16;
        hi = (hi + 0x8000u) & 0xffff0000u;
        r.u[i] = hi | lo;
    }
    return r.v;
}

// direct global -> LDS, 16 bytes per lane (LDS dst must be base + lane*16)
typedef __attribute__((address_space(1))) unsigned int ga_u32;
typedef __attribute__((address_space(3))) unsigned int ls_u32;
__device__ __forceinline__ void gload_lds16(const void* g, void* l) {
    __builtin_amdgcn_global_load_lds((ga_u32*)g, (ls_u32*)l, 16, 0, 0);
}

// ---------------------------------------------------------------- weights ---
__global__ void prep_weights(const float* __restrict__ Wcd, const float* __restrict__ Wsd,
                             const float* __restrict__ Wce, const float* __restrict__ Wse0,
                             const float* __restrict__ Wse1, const float* __restrict__ Wse3,
                             const float* __restrict__ Wdir, const float* __restrict__ Wpow,
                             const float* __restrict__ Wprop, char* __restrict__ wsb)
{
    __shared__ float s_wcd[32][32];
    __shared__ float s_wce[32][32];
    __shared__ float s_wsd[32][9];
    __shared__ float s_wse[32][4][9];
    __shared__ float s_wdir[4][32][4];
    const int tid = threadIdx.x;

    if (tid < 64) {
        int o = tid & 31;
        const float* src = (tid < 32) ? Wcd : Wce;
        float s = 0.f;
        for (int i = 0; i < 32; ++i) s += softplusf(src[o * 32 + i]);
        float inv = 1.f / s;
        for (int i = 0; i < 32; ++i) {
            float v = softplusf(src[o * 32 + i]) * inv;
            if (tid < 32) s_wcd[o][i] = v; else s_wce[o][i] = v;
        }
    }
    if (tid < 32) {
        int i = tid;
        float c0[3], c1[3]; float s = 0.f;
        for (int h = 0; h < 3; ++h) {
            c0[h] = softplusf(Wsd[(i * 3 + h) * 2 + 0]);
            c1[h] = softplusf(Wsd[(i * 3 + h) * 2 + 1]);
            s += 2.f * c0[h] + c1[h];
        }
        float inv = 1.f / s;
        for (int h = 0; h < 3; ++h) {
            s_wsd[i][h * 3 + 0] = c0[h] * inv;
            s_wsd[i][h * 3 + 1] = c1[h] * inv;
            s_wsd[i][h * 3 + 2] = c0[h] * inv;
        }
    }
    if (tid < 128) {
        int i = tid >> 2, d = tid & 3;
        float v[9];
        for (int h = 0; h < 3; ++h)
            for (int w = 0; w < 3; ++w) {
                float val;
                if (d == 0)      val = softplusf(Wse0[(i * 3 + h) * 3 + w]);
                else if (d == 1) val = softplusf(Wse1[(i * 3 + h) * 2 + (w == 1 ? 1 : 0)]);
                else if (d == 2) val = softplusf(Wse0[(i * 3 + h) * 3 + (2 - w)]);
                else             val = softplusf(Wse3[(i * 3 + h) * 2 + (w == 1 ? 1 : 0)]);
                v[h * 3 + w] = val;
            }
        float s = 0.f;
        for (int k = 0; k < 9; ++k) s += v[k];
        float inv = 1.f / s;
        for (int k = 0; k < 9; ++k) s_wse[i][d][k] = v[k] * inv;
    }
    if (tid < 128) {
        int p = tid >> 5, i = tid & 31;
        const int jmap[4][4] = {{0,1,2,3},{4,5,4,6},{2,1,0,3},{7,8,7,9}};
        float v[4]; float s = 0.f;
        for (int d = 0; d < 4; ++d) { v[d] = softplusf(Wdir[i * 10 + jmap[p][d]]); s += v[d]; }
        float inv = 1.f / s;
        for (int d = 0; d < 4; ++d) s_wdir[p][i][d] = v[d] * inv;
    }
    if (tid < 32) {
        int i = tid;
        float p0 = softplusf(Wpow[i*5+0]), p1 = softplusf(Wpow[i*5+1]), p2 = softplusf(Wpow[i*5+2]);
        float p3 = softplusf(Wpow[i*5+3]), p4 = softplusf(Wpow[i*5+4]);
        float* wp = (float*)(wsb + OFFB_WPOW) + (size_t)i * 8;
        wp[0]=p0; wp[1]=p2; wp[2]=p1; wp[3]=p4;   // s=0 (fwd)
        wp[4]=p1; wp[5]=p3; wp[6]=p0; wp[7]=p4;   // s=1 (bwd)
        float c0 = sigmf(Wprop[i*3+0]), c1 = sigmf(Wprop[i*3+1]), c2 = sigmf(Wprop[i*3+2]);
        float* pr = (float*)(wsb + OFFB_WPROP) + (size_t)i * 4;
        pr[0]=c1; pr[1]=c0; pr[2]=c1; pr[3]=c2;
    }
    __syncthreads();

    const int gtid = (int)blockIdx.x * 256 + tid;
    const int gstr = (int)(gridDim.x * blockDim.x);
    // conv_d weights in A-fragment bf16 layout: wdf[((tap*4+quad)*32+oc)*8+j], ic=quad*8+j
    unsigned short* wdf = (unsigned short*)(wsb + OFFB_WDFRAG);
    for (int g = gtid; g < 9 * 4 * 32; g += gstr) {
        int oc = g & 31, quad = (g >> 5) & 3, tap = g >> 7;
        unsigned int w[4];
        #pragma unroll
        for (int jp = 0; jp < 4; ++jp) {
            int i0 = quad * 8 + jp * 2;
            unsigned short lo = f2bf(s_wcd[oc][i0]     * s_wsd[i0][tap]);
            unsigned short hi = f2bf(s_wcd[oc][i0 + 1] * s_wsd[i0 + 1][tap]);
            w[jp] = (unsigned int)lo | ((unsigned int)hi << 16);
        }
        *(uint4*)(wdf + (size_t)g * 8) = make_uint4(w[0], w[1], w[2], w[3]);
    }
    // e-conv weights, bf16, A-fragment layout: wfrag[((tap*16+qq)*128+oc)*8+j]
    unsigned short* wfrag = (unsigned short*)(wsb + OFFB_WFRAG);
    for (int g = gtid; g < 9 * 16 * 128; g += gstr) {
        int oc = g & 127, qq = (g >> 7) & 15, tap = g >> 11;
        int o = oc >> 2, p = oc & 3;
        unsigned int w[4];
        #pragma unroll
        for (int jp = 0; jp < 4; ++jp) {
            int ic0 = qq * 8 + jp * 2;
            int i0 = ic0 >> 2, d0 = ic0 & 3;
            int i1 = (ic0 + 1) >> 2, d1 = (ic0 + 1) & 3;
            unsigned short lo = f2bf(s_wce[o][i0] * s_wdir[p][i0][d0] * s_wse[i0][d0][tap]);
            unsigned short hi = f2bf(s_wce[o][i1] * s_wdir[p][i1][d1] * s_wse[i1][d1][tap]);
            w[jp] = (unsigned int)lo | ((unsigned int)hi << 16);
        }
        *(uint4*)(wfrag + (size_t)g * 8) = make_uint4(w[0], w[1], w[2], w[3]);
    }
}

// -------------------------------------------------------------- ce/ece in ---
// Byte-exact r8 form (measured best; the r10 2-row variant regressed: 12x
// bank conflicts + halved occupancy outweighed the halo-fetch savings).
// 2 px/thread, 128-thread blocks, vectorized float4 stencil rows shared
// within the pixel pair; store phase via LDS replays the r2/r7 per-wave
// store pattern. Bit-identical outputs.
__global__ __launch_bounds__(128, 4) void prep_inputs(
    const float* __restrict__ xin, const float* __restrict__ ce,
    const float* __restrict__ ece, const char* __restrict__ wsb,
    unsigned short* __restrict__ ce_bf, unsigned short* __restrict__ ece_bf,
    unsigned short* __restrict__ x_bf)
{
    __shared__ unsigned short s_ce [64][4][8];   // 4 KB
    __shared__ unsigned short s_ece[64][4][8];   // 4 KB
    __shared__ unsigned short s_x[2][64][8];     // 2 KB

    const int tid = threadIdx.x;
    const int sp  = tid & 31;                // pair slot: px = 2sp, 2sp+1
    const int grp = tid >> 5;                // 0..3
    const int bx  = (int)blockIdx.x;
    const int xb  = bx * 64 + sp * 2;
    const int y   = (int)blockIdx.y;
    const int zz  = (int)blockIdx.z;         // b*4 + cb
    const int b   = zz >> 2;
    const int cb  = zz & 3;
    const int i0  = cb * 8 + grp * 2;        // channels i0, i0+1
    const float* wprop = (const float*)(wsb + OFFB_WPROP);
    const float* wpow  = (const float*)(wsb + OFFB_WPOW);
    const float LEPS = -66.43856f;           // log2(1e-20)

    // edge shift: left edge (xb==0) shifts window right by 1; right edge
    // (xb==190) shifts left by 1. val[j] covers x = xb-1+j, j=0..3.
    const int s  = (xb == 0) ? 1 : ((xb == 190) ? -1 : 0);
    const int xbase = xb - 1 + s;

    #pragma unroll
    for (int ii = 0; ii < 2; ++ii) {
        const int i = i0 + ii;
        const float* dcd = xin + ((size_t)(b * N + i)) * HW;
        const float* cd  = xin + ((size_t)((Bb + b) * N + i)) * HW;

        float cv[3][4], ld[3][4], dcent[2];
        #pragma unroll
        for (int r = 0; r < 3; ++r) {
            int yy = y + r - 1;
            f32x4 c4 = (f32x4){0.f, 0.f, 0.f, 0.f};
            f32x4 d4 = (f32x4){0.f, 0.f, 0.f, 0.f};
            if (yy >= 0 && yy < Hh) {                       // wave-uniform
                c4 = load4u(cd  + (size_t)yy * Ww + xbase);
                d4 = load4u(dcd + (size_t)yy * Ww + xbase);
            }
            #pragma unroll
            for (int j = 0; j < 4; ++j) {
                int xx = xb - 1 + j;
                bool vx = (xx >= 0) && (xx < Ww);
                int vi = (j - s) & 3;
                float c  = vx ? c4[vi] : 0.f;
                float dd = vx ? d4[vi] : 0.f;
                cv[r][j] = c;
                if (r == 1 && j >= 1 && j <= 2) dcent[j - 1] = dd;
                ld[r][j] = __builtin_amdgcn_logf(dd * frcp(c + EPSF) + EPSF);  // log2
            }
        }
        // x_bf center staging (raw values, as r7)
        #pragma unroll
        for (int k = 0; k < 2; ++k) {
            s_x[0][sp * 2 + k][grp * 2 + ii] = f2bf(dcent[k]);
            s_x[1][sp * 2 + k][grp * 2 + ii] = f2bf(cv[1][k + 1]);
        }
        #pragma unroll
        for (int d = 0; d < 4; ++d) {
            size_t idx = ((size_t)(b * 128 + i * 4 + d)) * HW + (size_t)y * Ww + xb;
            float2 c2 = *(const float2*)(ce + idx);
            float2 e2 = *(const float2*)(ece + idx);
            float p0 = wpow[i * 8 + d], p1 = wpow[i * 8 + 4 + d];
            float wp = wprop[i * 4 + d];
            #pragma unroll
            for (int k = 0; k < 2; ++k) {
                float lr, cn;
                if (d == 0)      { lr = ld[0][k]     - ld[2][k + 2]; cn = cv[0][k]     * cv[2][k + 2]; }
                else if (d == 1) { lr = ld[0][k + 1] - ld[2][k + 1]; cn = cv[0][k + 1] * cv[2][k + 1]; }
                else if (d == 2) { lr = ld[0][k + 2] - ld[2][k];     cn = cv[0][k + 2] * cv[2][k];     }
                else             { lr = ld[1][k + 2] - ld[1][k];     cn = cv[1][k + 2] * cv[1][k];     }
                float lrf = fmaxf(fminf(lr, 0.f), LEPS);    // == log2(clip(rf,EPS,1))
                float lrb = fmaxf(fminf(-lr, 0.f), LEPS);
                float ef = __builtin_amdgcn_exp2f(p0 * lrf);
                float eb = __builtin_amdgcn_exp2f(p1 * lrb);
                float en = fminf(ef, eb);
                float cr = (k == 0) ? c2.x : c2.y;
                float er = (k == 0) ? e2.x : e2.y;
                s_ce [sp * 2 + k][grp][ii * 4 + d] = f2bf(cr * wp + cn * (1.f - wp));
                s_ece[sp * 2 + k][grp][ii * 4 + d] = f2bf(er * wp + en * cn * (1.f - wp));
            }
        }
    }
    __syncthreads();
    // ce/ece stores: identical per-wave pattern to r2/r7 (64 consecutive px,
    // one uint4 at 256B stride per (grp,arr))
    #pragma unroll
    for (int it = 0; it < 4; ++it) {
        int flat = it * 128 + tid;           // 0..511
        int arr  = flat >> 8;
        int g    = (flat >> 6) & 3;
        int px   = flat & 63;
        size_t base = ((size_t)b * HW + (size_t)y * Ww + (size_t)bx * 64 + px) * 128
                      + (size_t)(cb * 8 + g * 2) * 4;
        const unsigned short* srcp = arr ? &s_ece[px][g][0] : &s_ce[px][g][0];
        *(uint4*)((arr ? ece_bf : ce_bf) + base) = *(const uint4*)srcp;
    }
    // x_bf: dense 16B-record stores into the (b,cb,t) planes (as r7)
    if (tid < 128) {
        int t = tid & 1, p = tid >> 1;
        size_t plane = (size_t)(b * 4 + cb) * 2 + t;
        size_t a = (plane * HW + (size_t)y * Ww + (size_t)bx * 64 + p) * 8;
        *(uint4*)(x_bf + a) = *(const uint4*)&s_x[t][p][0];
    }
}

// ------------------------------------------- 128->128 3x3 conv via MFMA -----
// r8 form (measured local optimum) + r11 XCD-aware tile swizzle: consecutive
// tiles round-robin across the 8 non-coherent XCD L2s by default, so halo
// rows shared by neighbor tiles miss L2 (FETCH 28 MB vs 18.9 unique = 1.48x
// halo factor). tile=(bx%8)*36+bx/8 gives each XCD 3 contiguous tile-rows.
__global__ __launch_bounds__(256, 3) void conv_e_mfma(
    const unsigned short* __restrict__ ce_bf, const unsigned short* __restrict__ ece_bf,
    const unsigned short* __restrict__ wfrag,
    float* __restrict__ ce_out, float* __restrict__ ece_out)
{
    const int z = blockIdx.z; const int t = z >> 1; const int b = z & 1;
    const unsigned short* in_bf = (t ? ece_bf : ce_bf) + (size_t)b * HW * 128;
    float* outp = t ? ece_out : ce_out;

    __shared__ unsigned short tile[180 * 128];   // 46080 B

    const int tid  = threadIdx.x;
    const int lane = tid & 63;
    const int l16  = lane & 15;
    const int quad = lane >> 4;
    const int wave = tid >> 6;
    const int ph   = wave >> 1;          // pixel-row half (rows 0-3 / 4-7)
    const int woc  = (wave & 1) * 64;    // oc half
    const int bx   = (int)blockIdx.x;
    const int tl   = (bx & 7) * 36 + (bx >> 3);   // XCD swizzle (288 = 8*36)
    const int x0 = (tl % 12) * 16;
    const int y0 = (tl / 12) * 8;

    const bool interior = (x0 >= 16 && x0 <= 160 && y0 >= 8 && y0 <= 176);
    if (interior) {
        #pragma unroll
        for (int it = 0; it < 12; ++it) {
            int idx = it * 256 + tid;
            if (idx < 180 * 16) {
                int p = idx >> 4, slot = idx & 15;
                int hy = p / 18, hx = p - hy * 18;
                int gy = y0 + hy - 1, gx = x0 + hx - 1;
                int csrc = slot ^ (p & 7);
                gload_lds16((const char*)in_bf + ((size_t)(gy * Ww + gx) * 16 + csrc) * 16,
                            (char*)tile + (size_t)idx * 16);
            }
        }
    } else {
        const uint4* gsrc = (const uint4*)in_bf;
        for (int idx = tid; idx < 180 * 16; idx += 256) {
            int p = idx >> 4, slot = idx & 15;
            int hy = p / 18, hx = p - hy * 18;
            int gy = y0 + hy - 1, gx = x0 + hx - 1;
            int csrc = slot ^ (p & 7);
            uint4 v = make_uint4(0u, 0u, 0u, 0u);
            if (gy >= 0 && gy < Hh && gx >= 0 && gx < Ww)
                v = gsrc[(size_t)(gy * Ww + gx) * 16 + csrc];
            *(uint4*)&tile[(size_t)idx * 8] = v;
        }
    }
    __syncthreads();

    f32x4 acc[4][4];   // [mt][nt]
    #pragma unroll
    for (int mt = 0; mt < 4; ++mt)
        #pragma unroll
        for (int nt = 0; nt < 4; ++nt) acc[mt][nt] = (f32x4){0.f, 0.f, 0.f, 0.f};

    for (int tap = 0; tap < 9; ++tap) {
        const int ky = tap / 3, kx = tap - ky * 3;
        #pragma unroll
        for (int q = 0; q < 4; ++q) {
            const int cq = q * 4 + quad;
            const unsigned short* wb = wfrag + (size_t)((tap * 16 + cq) * 128) * 8;
            bf16x8 a[4];
            #pragma unroll
            for (int mt = 0; mt < 4; ++mt)
                a[mt] = *(const bf16x8*)(wb + (size_t)(woc + mt * 16 + l16) * 8);
            #pragma unroll
            for (int nt = 0; nt < 4; ++nt) {
                int px = (ph * 4 + nt + ky) * 18 + l16 + kx;
                bf16x8 bv = *(const bf16x8*)&tile[px * 128 + ((cq ^ (px & 7)) << 3)];
                #pragma unroll
                for (int mt = 0; mt < 4; ++mt)
                    acc[mt][nt] = __builtin_amdgcn_mfma_f32_16x16x32_bf16(a[mt], bv, acc[mt][nt], 0, 0, 0);
            }
        }
    }

    #pragma unroll
    for (int mt = 0; mt < 4; ++mt)
        #pragma unroll
        for (int nt = 0; nt < 4; ++nt) {
            int y = y0 + ph * 4 + nt, x = x0 + l16;
            #pragma unroll
            for (int r = 0; r < 4; ++r) {
                int oc = woc + mt * 16 + quad * 4 + r;
                outp[((size_t)b * 128 + oc) * HW + (size_t)y * Ww + x] = acc[mt][nt][r];
            }
        }
}

// ----------------------- gated 32->32 conv via MFMA (dcd_out & cd_out) ------
// x-tile staged from x_bf planes via global_load_lds + chunk-XOR swizzle.
// r11: XCD-aware tile swizzle (576 = 8*72). E path unchanged (bit-identical).
__global__ __launch_bounds__(256) void conv_d_mfma(
    const unsigned short* __restrict__ x_bf, const unsigned short* __restrict__ wdfrag,
    const float* __restrict__ ece_out, const float* __restrict__ ce_out,
    float* __restrict__ out0)
{
    const int b = blockIdx.y;
    __shared__ unsigned short xt[108 * 64];      // 13824 B ([hp][t*32+i], XOR-swizzled)
    __shared__ unsigned short Ebf[4 * 64 * 40];  // 20480 B

    const int tid  = threadIdx.x;
    const int lane = tid & 63;
    const int l16  = lane & 15;
    const int quad = lane >> 4;
    const int wave = tid >> 6;
    const int t    = wave >> 1;      // 0: dcd, 1: cd
    const int nh   = wave & 1;       // pixel half
    const int bx   = (int)blockIdx.x;
    const int tl   = (bx & 7) * 72 + (bx >> 3);   // XCD swizzle (576 = 8*72)
    const int x0 = (tl % 12) * 16;
    const int y0 = (tl / 12) * 4;

    const bool interior = (x0 >= 16 && x0 <= 160 && y0 >= 4 && y0 <= 184);
    if (interior) {
        #pragma unroll
        for (int it = 0; it < 4; ++it) {
            int idx = it * 256 + tid;
            if (idx < 108 * 8) {
                int hp = idx >> 3, slot = idx & 7;
                int hy = hp / 18, hx = hp - hy * 18;
                int gy = y0 + hy - 1, gx = x0 + hx - 1;
                int csrc = slot ^ (hp & 7);
                size_t splane = (size_t)(b * 4 + (csrc & 3)) * 2 + (csrc >> 2);
                gload_lds16((const char*)x_bf + (splane * HW + (size_t)(gy * Ww + gx)) * 16,
                            (char*)xt + (size_t)idx * 16);
            }
        }
    } else {
        const uint4* gsrc = (const uint4*)x_bf;
        for (int idx = tid; idx < 108 * 8; idx += 256) {
            int hp = idx >> 3, slot = idx & 7;
            int hy = hp / 18, hx = hp - hy * 18;
            int gy = y0 + hy - 1, gx = x0 + hx - 1;
            int csrc = slot ^ (hp & 7);
            size_t splane = (size_t)(b * 4 + (csrc & 3)) * 2 + (csrc >> 2);
            uint4 v = make_uint4(0u, 0u, 0u, 0u);
            if (gy >= 0 && gy < Hh && gx >= 0 && gx < Ww)
                v = gsrc[splane * HW + (size_t)(gy * Ww + gx)];
            *(uint4*)&xt[(size_t)idx * 8] = v;
        }
    }
    // stage E (fp32 reads + rcp + clamp + f2bf)
    for (int idx = tid; idx < 32 * 64; idx += 256) {
        int px = idx & 15, py = (idx >> 4) & 3, i = idx >> 6;
        size_t gp = (size_t)(y0 + py) * Ww + x0 + px;
        int p = py * 16 + px;
        #pragma unroll
        for (int d = 0; d < 4; ++d) {
            size_t eidx = ((size_t)(b * 128 + i * 4 + d)) * HW + gp;
            float e = fminf(fmaxf(ece_out[eidx] * frcp(ce_out[eidx] + EPSF), EPSF), 1.f);
            Ebf[(d * 64 + p) * 40 + i] = f2bf(e);
        }
    }
    __syncthreads();

    f32x4 acc[2][2];   // [ntile][mtile]
    #pragma unroll
    for (int nt = 0; nt < 2; ++nt)
        #pragma unroll
        for (int mt = 0; mt < 2; ++mt) acc[nt][mt] = (f32x4){0.f, 0.f, 0.f, 0.f};

    const int cxt = t * 4 + quad;                      // x-chunk for this thread
    const int dmap[9] = {0, 1, 2, 3, 0, 3, 2, 1, 0};   // index 4 unused
    #pragma unroll
    for (int tap = 0; tap < 9; ++tap) {
        const int ky = tap / 3, kx = tap % 3;
        bf16x8 a0 = *(const bf16x8*)(wdfrag + (size_t)(((tap * 4 + quad) * 32) + l16) * 8);
        bf16x8 a1 = *(const bf16x8*)(wdfrag + (size_t)(((tap * 4 + quad) * 32) + 16 + l16) * 8);
        #pragma unroll
        for (int nt = 0; nt < 2; ++nt) {
            int p = nh * 32 + nt * 16 + l16;
            int py = p >> 4, px = p & 15;
            int hp = (py + ky) * 18 + px + kx;
            bf16x8 xv = *(const bf16x8*)&xt[hp * 64 + ((cxt ^ (hp & 7)) << 3)];
            bf16x8 g;
            if (tap == 4) g = xv;
            else {
                bf16x8 ev = *(const bf16x8*)&Ebf[(dmap[tap] * 64 + p) * 40 + quad * 8];
                g = bfmul8(xv, ev);
            }
            acc[nt][0] = __builtin_amdgcn_mfma_f32_16x16x32_bf16(a0, g, acc[nt][0], 0, 0, 0);
            acc[nt][1] = __builtin_amdgcn_mfma_f32_16x16x32_bf16(a1, g, acc[nt][1], 0, 0, 0);
        }
    }

    #pragma unroll
    for (int nt = 0; nt < 2; ++nt) {
        int p = nh * 32 + nt * 16 + l16;
        int py = p >> 4, px = p & 15;
        size_t gp = (size_t)(y0 + py) * Ww + x0 + px;
        #pragma unroll
        for (int mt = 0; mt < 2; ++mt)
            #pragma unroll
            for (int r = 0; r < 4; ++r) {
                int oc = mt * 16 + quad * 4 + r;
                out0[((size_t)((t * Bb + b) * N + oc)) * HW + gp] = acc[nt][mt][r];
            }
    }
}

extern "C" void kernel_launch(void* const* d_in, const int* in_sizes, int n_in,
                              void* d_out, int out_size, void* d_ws, size_t ws_size,
                              hipStream_t stream)
{
    const float* x     = (const float*)d_in[0];
    const float* ece   = (const float*)d_in[1];
    const float* ce    = (const float*)d_in[2];
    const float* Wcd   = (const float*)d_in[3];
    const float* Wsd   = (const float*)d_in[4];
    const float* Wce   = (const float*)d_in[5];
    const float* Wse0  = (const float*)d_in[6];
    const float* Wse1  = (const float*)d_in[7];
    const float* Wse3  = (const float*)d_in[8];
    const float* Wdir  = (const float*)d_in[9];
    const float* Wpow  = (const float*)d_in[10];
    const float* Wprop = (const float*)d_in[11];
    float* out = (float*)d_out;
    char* wsb  = (char*)d_ws;

    unsigned short* ce_bf  = (unsigned short*)(wsb + OFFB_CE_BF);
    unsigned short* ece_bf = (unsigned short*)(wsb + OFFB_ECE_BF);
    unsigned short* x_bf   = (unsigned short*)(wsb + OFFB_X_BF);
    unsigned short* wfrag  = (unsigned short*)(wsb + OFFB_WFRAG);
    unsigned short* wdfrag = (unsigned short*)(wsb + OFFB_WDFRAG);
    float* out0    = out;
    float* ece_out = out + OUT0_SZ;
    float* ce_out  = out + OUT0_SZ + EOUT_SZ;

    prep_weights<<<32, 256, 0, stream>>>(Wcd, Wsd, Wce, Wse0, Wse1, Wse3, Wdir, Wpow, Wprop, wsb);
    prep_inputs<<<dim3(3, Hh, Bb * 4), 128, 0, stream>>>(x, ce, ece, wsb, ce_bf, ece_bf, x_bf);
    conv_e_mfma<<<dim3(288, 1, 4), 256, 0, stream>>>(ce_bf, ece_bf, wfrag, ce_out, ece_out);
    conv_d_mfma<<<dim3(576, Bb), 256, 0, stream>>>(x_bf, wdfrag, ece_out, ce_out, out0);
}